// Round 3
// baseline (311.535 us; speedup 1.0000x reference)
//
#include <hip/hip_runtime.h>
#include <hip/hip_bf16.h>
#include <stdint.h>

// CrossAttention2d: n=16, c=1024, h=w=32 (hw=1024), S=256, c_enc=768, H=16, d=64.
// Pipeline: ln_stats -> norm+transpose(bf16) -> enc LN(bf16) -> cast weights ->
//   QT = ndT @ Wq^T + bq      (GEMM, Bt-form)
//   kv = enc_n @ Wkv^T + bkv  (GEMM, Bt-form)
//   vT = transpose(V)         (small kernel, [n][c][s])
//   attention per (n,head)    (swapped-QK^T MFMA, in-register softmax)
//   out = x + Wo @ y + bo     (GEMM, Bt=yT, fp32 out + residual)

typedef __bf16 bf16x8 __attribute__((ext_vector_type(8)));
typedef __bf16 bf16x4 __attribute__((ext_vector_type(4)));
typedef float f32x4 __attribute__((ext_vector_type(4)));

__device__ __forceinline__ void gload_lds16(const void* g, void* l) {
  __builtin_amdgcn_global_load_lds(
      (const __attribute__((address_space(1))) void*)(uintptr_t)g,
      (__attribute__((address_space(3))) void*)(unsigned int)(uintptr_t)l,
      16, 0, 0);
}

// ---------- LN stats over channels: mu/rstd per (n,p) ----------
__global__ __launch_bounds__(1024) void ln_stats_kernel(const float* __restrict__ x,
                                                        float* __restrict__ mu,
                                                        float* __restrict__ rstd) {
  int b = blockIdx.x;
  int n = b >> 4;
  int p0 = (b & 15) << 6;        // 64 pixels
  int t = threadIdx.x;
  int pl4 = t & 15;              // float4 index within the 64 px
  int cg = t >> 4;               // 0..63 c-group
  const f32x4* xp = (const f32x4*)(x + ((size_t)n << 20) + p0);
  f32x4 s = {0.f, 0.f, 0.f, 0.f}, s2 = {0.f, 0.f, 0.f, 0.f};
#pragma unroll
  for (int i = 0; i < 16; ++i) {
    int c = cg + (i << 6);
    f32x4 v = xp[(c << 8) + pl4];   // row stride 1024 floats = 256 float4
    s += v;
    s2 += v * v;
  }
  __shared__ f32x4 ls[64][16];
  __shared__ f32x4 ls2[64][16];
  ls[cg][pl4] = s;
  ls2[cg][pl4] = s2;
  __syncthreads();
  if (t < 64) {
    int q = t >> 4, p = t & 15;
    f32x4 a = {0.f, 0.f, 0.f, 0.f}, a2 = {0.f, 0.f, 0.f, 0.f};
#pragma unroll
    for (int i = 0; i < 16; ++i) {
      a += ls[(q << 4) + i][p];
      a2 += ls2[(q << 4) + i][p];
    }
    ls[q][p] = a;
    ls2[q][p] = a2;
  }
  __syncthreads();
  if (t < 16) {
    f32x4 tot = ls[0][t] + ls[1][t] + ls[2][t] + ls[3][t];
    f32x4 tot2 = ls2[0][t] + ls2[1][t] + ls2[2][t] + ls2[3][t];
    f32x4 m, r;
#pragma unroll
    for (int e = 0; e < 4; ++e) {
      float mm = tot[e] * (1.f / 1024.f);
      float var = tot2[e] * (1.f / 1024.f) - mm * mm;
      m[e] = mm;
      r[e] = rsqrtf(var + 1e-5f);
    }
    ((f32x4*)(mu + (n << 10) + p0))[t] = m;
    ((f32x4*)(rstd + (n << 10) + p0))[t] = r;
  }
}

// ---------- normalize + transpose: ndT[n][p][c] bf16 ----------
__global__ __launch_bounds__(256) void norm_transpose_kernel(
    const float* __restrict__ x, const float* __restrict__ mu,
    const float* __restrict__ rstd, const float* __restrict__ gamma,
    const float* __restrict__ beta, __bf16* __restrict__ ndT) {
  int n = blockIdx.z;
  int p0 = blockIdx.x << 6;
  int c0 = blockIdx.y << 6;
  __shared__ float tile[64][65];
  int t = threadIdx.x;
  int fc = t & 15;               // float4 col in p
  int rr = t >> 4;               // 0..15
  const float* xb = x + ((size_t)n << 20) + ((size_t)c0 << 10) + p0;
#pragma unroll
  for (int i = 0; i < 4; ++i) {
    int cl = (i << 4) + rr;
    f32x4 v = *(const f32x4*)(xb + ((size_t)cl << 10) + (fc << 2));
#pragma unroll
    for (int e = 0; e < 4; ++e) tile[cl][(fc << 2) + e] = v[e];
  }
  int cgp = t & 7;               // 8 c-groups of 8
  int pr = t >> 3;               // 0..31
  float g[8], bb[8];
#pragma unroll
  for (int k = 0; k < 8; ++k) {
    g[k] = gamma[c0 + (cgp << 3) + k];
    bb[k] = beta[c0 + (cgp << 3) + k];
  }
  __syncthreads();
#pragma unroll
  for (int it = 0; it < 2; ++it) {
    int pl = (it << 5) + pr;
    int gp = (n << 10) + p0 + pl;
    float m = mu[gp], r = rstd[gp];
    bf16x8 o;
#pragma unroll
    for (int k = 0; k < 8; ++k)
      o[k] = (__bf16)((tile[(cgp << 3) + k][pl] - m) * r * g[k] + bb[k]);
    *(bf16x8*)(ndT + ((size_t)gp << 10) + c0 + (cgp << 3)) = o;
  }
}

// ---------- enc LayerNorm (last dim 768) -> bf16 ----------
__global__ __launch_bounds__(256) void enc_ln_kernel(const float* __restrict__ enc,
    const float* __restrict__ gamma, const float* __restrict__ beta,
    __bf16* __restrict__ out) {
  int s = blockIdx.x, n = blockIdx.y;
  size_t base = ((size_t)n * 256 + s) * 768;
  int t = threadIdx.x;
  float v0 = enc[base + t], v1 = enc[base + t + 256], v2 = enc[base + t + 512];
  float sum = v0 + v1 + v2, sq = v0 * v0 + v1 * v1 + v2 * v2;
#pragma unroll
  for (int off = 32; off; off >>= 1) {
    sum += __shfl_down(sum, off);
    sq  += __shfl_down(sq, off);
  }
  __shared__ float red[8];
  int w = t >> 6;
  if ((t & 63) == 0) { red[w] = sum; red[4 + w] = sq; }
  __syncthreads();
  float tot  = red[0] + red[1] + red[2] + red[3];
  float tot2 = red[4] + red[5] + red[6] + red[7];
  float m = tot * (1.f / 768.f);
  float var = tot2 * (1.f / 768.f) - m * m;
  float rs = rsqrtf(var + 1e-5f);
  out[base + t]       = (__bf16)((v0 - m) * rs * gamma[t] + beta[t]);
  out[base + t + 256] = (__bf16)((v1 - m) * rs * gamma[t + 256] + beta[t + 256]);
  out[base + t + 512] = (__bf16)((v2 - m) * rs * gamma[t + 512] + beta[t + 512]);
}

// ---------- fp32 -> bf16 cast ----------
__global__ __launch_bounds__(256) void cast_bf16_kernel(const float* __restrict__ in,
                                                        __bf16* __restrict__ out, int count) {
  int stride = gridDim.x * 256;
  for (int i = blockIdx.x * 256 + threadIdx.x; i < count; i += stride)
    out[i] = (__bf16)in[i];
}

// ---------- V transpose: kv[n][s][1024+c] -> vT[n][c][s] ----------
__global__ __launch_bounds__(256) void v_transpose_kernel(const __bf16* __restrict__ kv,
                                                          __bf16* __restrict__ vT) {
  int h = blockIdx.x, n = blockIdx.y;
  __shared__ __bf16 tile[64][264];
  int t = threadIdx.x;
  const __bf16* src = kv + ((size_t)n << 19) + 1024 + (h << 6);
#pragma unroll
  for (int i = 0; i < 8; ++i) {
    int s = (i << 5) + (t >> 3);
    int d8 = (t & 7) << 3;
    bf16x8 v = *(const bf16x8*)(src + ((size_t)s << 11) + d8);
#pragma unroll
    for (int j = 0; j < 8; ++j) tile[d8 + j][s] = v[j];
  }
  __syncthreads();
  __bf16* dst = vT + (((size_t)(n << 10) + (h << 6)) << 8);
  int d = t >> 2, s0 = (t & 3) << 6;
#pragma unroll
  for (int j = 0; j < 8; ++j)
    *(bf16x8*)(dst + ((size_t)d << 8) + s0 + (j << 3)) = *(const bf16x8*)&tile[d][s0 + (j << 3)];
}

// ---------- GEMM: C[M][N] = A[M][K] * Bt[N][K]^T (+bias, +resid) ----------
template <int EPI>
__global__ __launch_bounds__(256) void gemm_bt_kernel(
    const __bf16* __restrict__ A, const __bf16* __restrict__ Bt,
    const float* __restrict__ bias, const float* __restrict__ resid,
    void* __restrict__ Cout, int M, int N, int K,
    size_t sA, size_t sB, size_t sC, size_t sR) {
  int n0 = blockIdx.x << 7;
  int m0 = blockIdx.y << 7;
  int bz = blockIdx.z;
  const __bf16* Ab = A + sA * bz;
  const __bf16* Bb = Bt + sB * bz;

  int tid = threadIdx.x;
  int w = tid >> 6, lane = tid & 63;
  int l15 = lane & 15, hi = lane >> 4;
  int wr = w >> 1, wc = w & 1;

  __shared__ __align__(16) __bf16 lA[128 * 64];
  __shared__ __align__(16) __bf16 lB[128 * 64];

  f32x4 acc[4][4] = {};
  int xorkey = (l15 & 7) << 3;

  for (int kt = 0; kt < K; kt += 64) {
#pragma unroll
    for (int i = 0; i < 4; ++i) {
      int e = ((i << 8) + tid) << 3;
      int r = e >> 6;
      int c = e & 63;
      int cs = c ^ ((r & 7) << 3);
      gload_lds16(Ab + (size_t)(m0 + r) * K + kt + cs, &lA[e]);
    }
#pragma unroll
    for (int i = 0; i < 4; ++i) {
      int e = ((i << 8) + tid) << 3;
      int r = e >> 6;
      int c = e & 63;
      int cs = c ^ ((r & 7) << 3);
      gload_lds16(Bb + (size_t)(n0 + r) * K + kt + cs, &lB[e]);
    }
    __syncthreads();
#pragma unroll
    for (int kk = 0; kk < 2; ++kk) {
      int ko = (kk << 5) + (hi << 3);
      bf16x8 af[4], bfr[4];
#pragma unroll
      for (int mi = 0; mi < 4; ++mi)
        af[mi] = *(const bf16x8*)&lA[(((wr << 6) + (mi << 4) + l15) << 6) + (ko ^ xorkey)];
#pragma unroll
      for (int ni = 0; ni < 4; ++ni)
        bfr[ni] = *(const bf16x8*)&lB[(((wc << 6) + (ni << 4) + l15) << 6) + (ko ^ xorkey)];
#pragma unroll
      for (int mi = 0; mi < 4; ++mi)
#pragma unroll
        for (int ni = 0; ni < 4; ++ni)
          acc[mi][ni] = __builtin_amdgcn_mfma_f32_16x16x32_bf16(af[mi], bfr[ni], acc[mi][ni], 0, 0, 0);
    }
    __syncthreads();
  }

#pragma unroll
  for (int mi = 0; mi < 4; ++mi) {
#pragma unroll
    for (int ni = 0; ni < 4; ++ni) {
      int col = n0 + (wc << 6) + (ni << 4) + l15;
      int rbase = m0 + (wr << 6) + (mi << 4) + (hi << 2);
      if (EPI == 0) {
        float bb = bias[col];
        __bf16* C = (__bf16*)Cout + sC * bz;
#pragma unroll
        for (int j = 0; j < 4; ++j)
          C[(size_t)(rbase + j) * N + col] = (__bf16)(acc[mi][ni][j] + bb);
      } else {
        float* C = (float*)Cout + sC * bz;
        const float* R = resid + sR * bz;
#pragma unroll
        for (int j = 0; j < 4; ++j) {
          int row = rbase + j;
          C[(size_t)row * N + col] = acc[mi][ni][j] + bias[row] + R[(size_t)row * N + col];
        }
      }
    }
  }
}

// ---------- attention: swapped QK^T, in-register softmax ----------
// Block = (n, h, 64-q tile), 4 waves x 16 q. LDS ~34 KB -> 4 blocks/CU.
// S^T = mfma(A=K, B=Q): lane(hi,l15) holds S[key=16ni+4hi+j][q=q0w+l15].
// Softmax per query = in-lane over 64 regs + shfl_xor(16,32).
// P staged in per-wave LDS (XOR-swizzled), PV reads V fragments from vT global.
__global__ __launch_bounds__(256, 4) void attn_kernel(
    const __bf16* __restrict__ QT,   // [n][1024][1024]
    const __bf16* __restrict__ kv,   // [n][256][2048] (K part: cols 0..1023)
    const __bf16* __restrict__ vT,   // [n][1024][256]
    const int* __restrict__ padding, // [n][256]
    __bf16* __restrict__ yT) {       // [n][1024][1024]
  int qb = blockIdx.x, h = blockIdx.y, n = blockIdx.z;
  int tid = threadIdx.x;
  int w = tid >> 6, lane = tid & 63;
  int l15 = lane & 15, hi = lane >> 4;

  __shared__ __align__(16) float lpad[256];
  __shared__ __align__(16) __bf16 lP[4][16][256];

  lpad[tid] = 10000.f * (float)padding[(n << 8) + tid];

  // Q as B-operand fragments (col=q=l15, k=d=8hi+j)
  int q0w = (qb << 6) + (w << 4);
  const __bf16* qsrc = QT + ((size_t)((n << 10) + q0w + l15) << 10) + (h << 6) + (hi << 3);
  bf16x8 bq0 = *(const bf16x8*)qsrc;
  bf16x8 bq1 = *(const bf16x8*)(qsrc + 32);
  __syncthreads();

  // S^T: K rows from global (L2-resident, 32 KB/head)
  const __bf16* kbase = kv + ((size_t)n << 19) + (h << 6) + (hi << 3);
  f32x4 sa[16];
#pragma unroll
  for (int ni = 0; ni < 16; ++ni) {
    const __bf16* kr = kbase + ((size_t)((ni << 4) + l15) << 11);
    bf16x8 a0 = *(const bf16x8*)kr;
    bf16x8 a1 = *(const bf16x8*)(kr + 32);
    f32x4 z = {0.f, 0.f, 0.f, 0.f};
    z = __builtin_amdgcn_mfma_f32_16x16x32_bf16(a0, bq0, z, 0, 0, 0);
    sa[ni] = __builtin_amdgcn_mfma_f32_16x16x32_bf16(a1, bq1, z, 0, 0, 0);
  }

  // mask + max (lane holds keys 16ni+4hi+{0..3} for query l15)
  float mx = -3.4e38f;
#pragma unroll
  for (int ni = 0; ni < 16; ++ni) {
    f32x4 pm = *(const f32x4*)&lpad[(ni << 4) + (hi << 2)];
#pragma unroll
    for (int j = 0; j < 4; ++j) {
      float v = sa[ni][j] * 0.125f - pm[j];
      sa[ni][j] = v;
      mx = fmaxf(mx, v);
    }
  }
  mx = fmaxf(mx, __shfl_xor(mx, 16));
  mx = fmaxf(mx, __shfl_xor(mx, 32));
  float sum = 0.f;
#pragma unroll
  for (int ni = 0; ni < 16; ++ni)
#pragma unroll
    for (int j = 0; j < 4; ++j) {
      float p = __expf(sa[ni][j] - mx);
      sa[ni][j] = p;
      sum += p;
    }
  sum += __shfl_xor(sum, 16);
  sum += __shfl_xor(sum, 32);
  float dinv = 1.f / sum;   // for query q0w + l15

  // P -> per-wave LDS (bf16, row-XOR swizzle; no barrier: wave-private)
  int xr = (l15 & 7) << 3;
  __bf16* lPw = &lP[w][l15][0];
#pragma unroll
  for (int ni = 0; ni < 16; ++ni) {
    bf16x4 pk;
#pragma unroll
    for (int j = 0; j < 4; ++j) pk[j] = (__bf16)sa[ni][j];
    *(bf16x4*)&lPw[(((ni << 4) + (hi << 2)) ^ xr)] = pk;
  }

  // y = P V : A = P (row=q=l15, k=32kc+8hi+j), B = V from vT (col=d=l15)
  const __bf16* vbase = vT + ((((size_t)(n << 10)) + (h << 6) + l15) << 8) + (hi << 3);
  f32x4 ya[4] = {};
#pragma unroll
  for (int kc = 0; kc < 8; ++kc) {
    bf16x8 pa = *(const bf16x8*)&lPw[(((kc << 5) + (hi << 3)) ^ xr)];
#pragma unroll
    for (int nd = 0; nd < 4; ++nd) {
      bf16x8 vb = *(const bf16x8*)(vbase + ((size_t)nd << 12) + (kc << 5));
      ya[nd] = __builtin_amdgcn_mfma_f32_16x16x32_bf16(pa, vb, ya[nd], 0, 0, 0);
    }
  }

  // dinv for output row q = q0w+4hi+j lives at lane 4hi+j
  float dq[4];
#pragma unroll
  for (int j = 0; j < 4; ++j) dq[j] = __shfl(dinv, (hi << 2) + j);

#pragma unroll
  for (int nd = 0; nd < 4; ++nd) {
    int d = (h << 6) + (nd << 4) + l15;
#pragma unroll
    for (int j = 0; j < 4; ++j) {
      int q = q0w + (hi << 2) + j;
      yT[((size_t)((n << 10) + q) << 10) + d] = (__bf16)(ya[nd][j] * dq[j]);
    }
  }
}

extern "C" void kernel_launch(void* const* d_in, const int* in_sizes, int n_in,
                              void* d_out, int out_size, void* d_ws, size_t ws_size,
                              hipStream_t stream) {
  const float* x         = (const float*)d_in[0];
  const float* enc       = (const float*)d_in[1];
  const int*   padding   = (const int*)d_in[2];
  const float* gamma_dec = (const float*)d_in[3];
  const float* beta_dec  = (const float*)d_in[4];
  const float* gamma_enc = (const float*)d_in[5];
  const float* beta_enc  = (const float*)d_in[6];
  const float* Wq        = (const float*)d_in[7];
  const float* bq        = (const float*)d_in[8];
  const float* Wkv       = (const float*)d_in[9];
  const float* bkv       = (const float*)d_in[10];
  const float* Wo        = (const float*)d_in[11];
  const float* bo        = (const float*)d_in[12];
  float* out = (float*)d_out;

  char* ws = (char*)d_ws;
  // layout (bytes): ndT/yT alias 0..32M, QT 32M..64M, kv 64M..80M,
  // encn 80M..86.3M (dead after kv-GEMM) overlapped by vT 80M..88M,
  // WqB, WkvB, WoB, mu, rstd. total ~97.6 MB.
  __bf16* ndT  = (__bf16*)(ws);
  __bf16* yT   = (__bf16*)(ws);                 // reuse: ndT dead after Q-GEMM
  __bf16* QT   = (__bf16*)(ws + 33554432);
  __bf16* kvb  = (__bf16*)(ws + 67108864);
  __bf16* encn = (__bf16*)(ws + 83886080);
  __bf16* vT   = (__bf16*)(ws + 83886080);      // reuse: encn dead after kv-GEMM
  __bf16* WqB  = (__bf16*)(ws + 92274688);
  __bf16* WkvB = (__bf16*)(ws + 94371840);
  __bf16* WoB  = (__bf16*)(ws + 97517568);
  float*  mu   = (float*)(ws + 99614720);
  float*  rstd = (float*)(ws + 99680256);

  ln_stats_kernel<<<256, 1024, 0, stream>>>(x, mu, rstd);
  norm_transpose_kernel<<<dim3(16, 16, 16), 256, 0, stream>>>(x, mu, rstd, gamma_dec, beta_dec, ndT);
  enc_ln_kernel<<<dim3(256, 16), 256, 0, stream>>>(enc, gamma_enc, beta_enc, encn);
  cast_bf16_kernel<<<512, 256, 0, stream>>>(Wq, WqB, 1024 * 1024);
  cast_bf16_kernel<<<512, 256, 0, stream>>>(Wkv, WkvB, 2048 * 768);
  cast_bf16_kernel<<<512, 256, 0, stream>>>(Wo, WoB, 1024 * 1024);

  // QT[n][p][o] = ndT[n] @ Wq^T + bq
  gemm_bt_kernel<0><<<dim3(8, 8, 16), 256, 0, stream>>>(
      ndT, WqB, bq, nullptr, QT, 1024, 1024, 1024,
      (size_t)1024 * 1024, 0, (size_t)1024 * 1024, 0);
  // kv[n][s][j] = encn[n] @ Wkv^T + bkv
  gemm_bt_kernel<0><<<dim3(16, 2, 16), 256, 0, stream>>>(
      encn, WkvB, bkv, nullptr, kvb, 256, 2048, 768,
      (size_t)256 * 768, 0, (size_t)256 * 2048, 0);

  v_transpose_kernel<<<dim3(16, 16), 256, 0, stream>>>(kvb, vT);

  attn_kernel<<<dim3(16, 16, 16), 256, 0, stream>>>(QT, kvb, vT, padding, yT);

  // out[n][o][p] = x + Wo @ y + bo   (Bt = yT[n][p][c])
  gemm_bt_kernel<1><<<dim3(8, 8, 16), 256, 0, stream>>>(
      WoB, yT, bo, x, out, 1024, 1024, 1024,
      0, (size_t)1024 * 1024, (size_t)1024 * 1024, (size_t)1024 * 1024);
}

// Round 4
// 231.026 us; speedup vs baseline: 1.3485x; 1.3485x over previous
//
#include <hip/hip_runtime.h>
#include <hip/hip_bf16.h>
#include <stdint.h>

// CrossAttention2d: n=16, c=1024, h=w=32 (hw=1024), S=256, c_enc=768, H=16, d=64.
// Pipeline: ln_stats -> norm+transpose(bf16) -> enc LN(bf16) -> cast weights ->
//   QT = ndT @ Wq^T + bq      (GEMM, Bt-form)
//   kv = enc_n @ Wkv^T + bkv  (GEMM, Bt-form)
//   vT = transpose(V)         (small kernel, [n][c][s])
//   attention per (h, qtile, n): K+V^T staged in LDS (66 KB, 2 blocks/CU),
//     swapped QK^T (S^T), in-register softmax, P through LDS (aliases K buf)
//   out = x + Wo @ y + bo     (GEMM, Bt=yT, fp32 out + residual)

typedef __bf16 bf16x8 __attribute__((ext_vector_type(8)));
typedef __bf16 bf16x4 __attribute__((ext_vector_type(4)));
typedef float f32x4 __attribute__((ext_vector_type(4)));

__device__ __forceinline__ void gload_lds16(const void* g, void* l) {
  __builtin_amdgcn_global_load_lds(
      (const __attribute__((address_space(1))) void*)(uintptr_t)g,
      (__attribute__((address_space(3))) void*)(unsigned int)(uintptr_t)l,
      16, 0, 0);
}

// ---------- LN stats over channels: mu/rstd per (n,p) ----------
__global__ __launch_bounds__(1024) void ln_stats_kernel(const float* __restrict__ x,
                                                        float* __restrict__ mu,
                                                        float* __restrict__ rstd) {
  int b = blockIdx.x;
  int n = b >> 4;
  int p0 = (b & 15) << 6;        // 64 pixels
  int t = threadIdx.x;
  int pl4 = t & 15;              // float4 index within the 64 px
  int cg = t >> 4;               // 0..63 c-group
  const f32x4* xp = (const f32x4*)(x + ((size_t)n << 20) + p0);
  f32x4 s = {0.f, 0.f, 0.f, 0.f}, s2 = {0.f, 0.f, 0.f, 0.f};
#pragma unroll
  for (int i = 0; i < 16; ++i) {
    int c = cg + (i << 6);
    f32x4 v = xp[(c << 8) + pl4];   // row stride 1024 floats = 256 float4
    s += v;
    s2 += v * v;
  }
  __shared__ f32x4 ls[64][16];
  __shared__ f32x4 ls2[64][16];
  ls[cg][pl4] = s;
  ls2[cg][pl4] = s2;
  __syncthreads();
  if (t < 64) {
    int q = t >> 4, p = t & 15;
    f32x4 a = {0.f, 0.f, 0.f, 0.f}, a2 = {0.f, 0.f, 0.f, 0.f};
#pragma unroll
    for (int i = 0; i < 16; ++i) {
      a += ls[(q << 4) + i][p];
      a2 += ls2[(q << 4) + i][p];
    }
    ls[q][p] = a;
    ls2[q][p] = a2;
  }
  __syncthreads();
  if (t < 16) {
    f32x4 tot = ls[0][t] + ls[1][t] + ls[2][t] + ls[3][t];
    f32x4 tot2 = ls2[0][t] + ls2[1][t] + ls2[2][t] + ls2[3][t];
    f32x4 m, r;
#pragma unroll
    for (int e = 0; e < 4; ++e) {
      float mm = tot[e] * (1.f / 1024.f);
      float var = tot2[e] * (1.f / 1024.f) - mm * mm;
      m[e] = mm;
      r[e] = rsqrtf(var + 1e-5f);
    }
    ((f32x4*)(mu + (n << 10) + p0))[t] = m;
    ((f32x4*)(rstd + (n << 10) + p0))[t] = r;
  }
}

// ---------- normalize + transpose: ndT[n][p][c] bf16 ----------
__global__ __launch_bounds__(256) void norm_transpose_kernel(
    const float* __restrict__ x, const float* __restrict__ mu,
    const float* __restrict__ rstd, const float* __restrict__ gamma,
    const float* __restrict__ beta, __bf16* __restrict__ ndT) {
  int n = blockIdx.z;
  int p0 = blockIdx.x << 6;
  int c0 = blockIdx.y << 6;
  __shared__ float tile[64][65];
  int t = threadIdx.x;
  int fc = t & 15;               // float4 col in p
  int rr = t >> 4;               // 0..15
  const float* xb = x + ((size_t)n << 20) + ((size_t)c0 << 10) + p0;
#pragma unroll
  for (int i = 0; i < 4; ++i) {
    int cl = (i << 4) + rr;
    f32x4 v = *(const f32x4*)(xb + ((size_t)cl << 10) + (fc << 2));
#pragma unroll
    for (int e = 0; e < 4; ++e) tile[cl][(fc << 2) + e] = v[e];
  }
  int cgp = t & 7;               // 8 c-groups of 8
  int pr = t >> 3;               // 0..31
  float g[8], bb[8];
#pragma unroll
  for (int k = 0; k < 8; ++k) {
    g[k] = gamma[c0 + (cgp << 3) + k];
    bb[k] = beta[c0 + (cgp << 3) + k];
  }
  __syncthreads();
#pragma unroll
  for (int it = 0; it < 2; ++it) {
    int pl = (it << 5) + pr;
    int gp = (n << 10) + p0 + pl;
    float m = mu[gp], r = rstd[gp];
    bf16x8 o;
#pragma unroll
    for (int k = 0; k < 8; ++k)
      o[k] = (__bf16)((tile[(cgp << 3) + k][pl] - m) * r * g[k] + bb[k]);
    *(bf16x8*)(ndT + ((size_t)gp << 10) + c0 + (cgp << 3)) = o;
  }
}

// ---------- enc LayerNorm (last dim 768) -> bf16 ----------
__global__ __launch_bounds__(256) void enc_ln_kernel(const float* __restrict__ enc,
    const float* __restrict__ gamma, const float* __restrict__ beta,
    __bf16* __restrict__ out) {
  int s = blockIdx.x, n = blockIdx.y;
  size_t base = ((size_t)n * 256 + s) * 768;
  int t = threadIdx.x;
  float v0 = enc[base + t], v1 = enc[base + t + 256], v2 = enc[base + t + 512];
  float sum = v0 + v1 + v2, sq = v0 * v0 + v1 * v1 + v2 * v2;
#pragma unroll
  for (int off = 32; off; off >>= 1) {
    sum += __shfl_down(sum, off);
    sq  += __shfl_down(sq, off);
  }
  __shared__ float red[8];
  int w = t >> 6;
  if ((t & 63) == 0) { red[w] = sum; red[4 + w] = sq; }
  __syncthreads();
  float tot  = red[0] + red[1] + red[2] + red[3];
  float tot2 = red[4] + red[5] + red[6] + red[7];
  float m = tot * (1.f / 768.f);
  float var = tot2 * (1.f / 768.f) - m * m;
  float rs = rsqrtf(var + 1e-5f);
  out[base + t]       = (__bf16)((v0 - m) * rs * gamma[t] + beta[t]);
  out[base + t + 256] = (__bf16)((v1 - m) * rs * gamma[t + 256] + beta[t + 256]);
  out[base + t + 512] = (__bf16)((v2 - m) * rs * gamma[t + 512] + beta[t + 512]);
}

// ---------- fp32 -> bf16 cast ----------
__global__ __launch_bounds__(256) void cast_bf16_kernel(const float* __restrict__ in,
                                                        __bf16* __restrict__ out, int count) {
  int stride = gridDim.x * 256;
  for (int i = blockIdx.x * 256 + threadIdx.x; i < count; i += stride)
    out[i] = (__bf16)in[i];
}

// ---------- V transpose: kv[n][s][1024+c] -> vT[n][c][s] ----------
__global__ __launch_bounds__(256) void v_transpose_kernel(const __bf16* __restrict__ kv,
                                                          __bf16* __restrict__ vT) {
  int h = blockIdx.x, n = blockIdx.y;
  __shared__ __bf16 tile[64][264];
  int t = threadIdx.x;
  const __bf16* src = kv + ((size_t)n << 19) + 1024 + (h << 6);
#pragma unroll
  for (int i = 0; i < 8; ++i) {
    int s = (i << 5) + (t >> 3);
    int d8 = (t & 7) << 3;
    bf16x8 v = *(const bf16x8*)(src + ((size_t)s << 11) + d8);
#pragma unroll
    for (int j = 0; j < 8; ++j) tile[d8 + j][s] = v[j];
  }
  __syncthreads();
  __bf16* dst = vT + (((size_t)(n << 10) + (h << 6)) << 8);
  int d = t >> 2, s0 = (t & 3) << 6;
#pragma unroll
  for (int j = 0; j < 8; ++j)
    *(bf16x8*)(dst + ((size_t)d << 8) + s0 + (j << 3)) = *(const bf16x8*)&tile[d][s0 + (j << 3)];
}

// ---------- GEMM: C[M][N] = A[M][K] * Bt[N][K]^T (+bias, +resid) ----------
template <int EPI>
__global__ __launch_bounds__(256) void gemm_bt_kernel(
    const __bf16* __restrict__ A, const __bf16* __restrict__ Bt,
    const float* __restrict__ bias, const float* __restrict__ resid,
    void* __restrict__ Cout, int M, int N, int K,
    size_t sA, size_t sB, size_t sC, size_t sR) {
  int n0 = blockIdx.x << 7;
  int m0 = blockIdx.y << 7;
  int bz = blockIdx.z;
  const __bf16* Ab = A + sA * bz;
  const __bf16* Bb = Bt + sB * bz;

  int tid = threadIdx.x;
  int w = tid >> 6, lane = tid & 63;
  int l15 = lane & 15, hi = lane >> 4;
  int wr = w >> 1, wc = w & 1;

  __shared__ __align__(16) __bf16 lA[128 * 64];
  __shared__ __align__(16) __bf16 lB[128 * 64];

  f32x4 acc[4][4] = {};
  int xorkey = (l15 & 7) << 3;

  for (int kt = 0; kt < K; kt += 64) {
#pragma unroll
    for (int i = 0; i < 4; ++i) {
      int e = ((i << 8) + tid) << 3;
      int r = e >> 6;
      int c = e & 63;
      int cs = c ^ ((r & 7) << 3);
      gload_lds16(Ab + (size_t)(m0 + r) * K + kt + cs, &lA[e]);
    }
#pragma unroll
    for (int i = 0; i < 4; ++i) {
      int e = ((i << 8) + tid) << 3;
      int r = e >> 6;
      int c = e & 63;
      int cs = c ^ ((r & 7) << 3);
      gload_lds16(Bb + (size_t)(n0 + r) * K + kt + cs, &lB[e]);
    }
    __syncthreads();
#pragma unroll
    for (int kk = 0; kk < 2; ++kk) {
      int ko = (kk << 5) + (hi << 3);
      bf16x8 af[4], bfr[4];
#pragma unroll
      for (int mi = 0; mi < 4; ++mi)
        af[mi] = *(const bf16x8*)&lA[(((wr << 6) + (mi << 4) + l15) << 6) + (ko ^ xorkey)];
#pragma unroll
      for (int ni = 0; ni < 4; ++ni)
        bfr[ni] = *(const bf16x8*)&lB[(((wc << 6) + (ni << 4) + l15) << 6) + (ko ^ xorkey)];
#pragma unroll
      for (int mi = 0; mi < 4; ++mi)
#pragma unroll
        for (int ni = 0; ni < 4; ++ni)
          acc[mi][ni] = __builtin_amdgcn_mfma_f32_16x16x32_bf16(af[mi], bfr[ni], acc[mi][ni], 0, 0, 0);
    }
    __syncthreads();
  }

#pragma unroll
  for (int mi = 0; mi < 4; ++mi) {
#pragma unroll
    for (int ni = 0; ni < 4; ++ni) {
      int col = n0 + (wc << 6) + (ni << 4) + l15;
      int rbase = m0 + (wr << 6) + (mi << 4) + (hi << 2);
      if (EPI == 0) {
        float bb = bias[col];
        __bf16* C = (__bf16*)Cout + sC * bz;
#pragma unroll
        for (int j = 0; j < 4; ++j)
          C[(size_t)(rbase + j) * N + col] = (__bf16)(acc[mi][ni][j] + bb);
      } else {
        float* C = (float*)Cout + sC * bz;
        const float* R = resid + sR * bz;
#pragma unroll
        for (int j = 0; j < 4; ++j) {
          int row = rbase + j;
          C[(size_t)row * N + col] = acc[mi][ni][j] + bias[row] + R[(size_t)row * N + col];
        }
      }
    }
  }
}

// ---------- attention: LDS-staged K/V^T, swapped QK^T, P aliases K ----------
// Block = (h, qb, n): grid.x = h so all 16 qb blocks of one (n,h) share an XCD
// (linear id = h + 16*qb + 256*n; XCD = id % 8 = h % 8) -> K/V L2 locality.
// LDS: lKP 32K (K, then P after barrier) + lVt 32K + lpad 1K = 66 KB -> 2 blk/CU.
// S^T = mfma(A=K_lds, B=Q_rows): lane(hi,l15) holds S[q=l15][key=16kg+4hi+j].
// Softmax in-lane (64 keys) + shfl_xor(16,32). P rows wave-private in lKP.
__global__ __launch_bounds__(256, 2) void attn_kernel(
    const __bf16* __restrict__ QT,   // [n][1024][1024]
    const __bf16* __restrict__ kv,   // [n][256][2048] (K part: cols 0..1023)
    const __bf16* __restrict__ vT,   // [n][1024][256]
    const int* __restrict__ padding, // [n][256]
    __bf16* __restrict__ yT) {       // [n][1024][1024]
  int h = blockIdx.x, qb = blockIdx.y, n = blockIdx.z;
  int tid = threadIdx.x;
  int w = tid >> 6, lane = tid & 63;
  int l15 = lane & 15, hi = lane >> 4;
  int xk = (l15 & 7) << 3;

  __shared__ __align__(16) __bf16 lKP[256 * 64];  // K [256 keys][64 d]; later P [64 q][256 keys]
  __shared__ __align__(16) __bf16 lVt[64 * 256];  // V^T [64 d][256 keys]
  __shared__ __align__(16) float lpad[256];

  const __bf16* kvb = kv + ((size_t)n << 19);
  // stage K (swizzled source, linear LDS): lKP[r][c] = K[r][c ^ ((r&7)<<3)]
#pragma unroll
  for (int i = 0; i < 8; ++i) {
    int e = ((i << 8) + tid) << 3;
    int r = e >> 6;
    int c = e & 63;
    int cs = c ^ ((r & 7) << 3);
    gload_lds16(kvb + ((size_t)r << 11) + (h << 6) + cs, &lKP[e]);
  }
  // stage V^T from vT global (swizzled source): lVt[r][c] = Vt[r][c ^ ((r&7)<<3)]
  const __bf16* vtb = vT + (((size_t)(n << 10) + (h << 6)) << 8);
#pragma unroll
  for (int i = 0; i < 8; ++i) {
    int e = ((i << 8) + tid) << 3;
    int r = e >> 8;
    int c = e & 255;
    int cs = c ^ ((r & 7) << 3);
    gload_lds16(vtb + ((size_t)r << 8) + cs, &lVt[e]);
  }
  lpad[tid] = 10000.f * (float)padding[(n << 8) + tid];

  // Q as B-operand fragments (col=q=l15, k=d=8hi+jj), line-coalesced
  int q0w = (qb << 6) + (w << 4);
  const __bf16* qsrc = QT + ((size_t)((n << 10) + q0w + l15) << 10) + (h << 6) + (hi << 3);
  bf16x8 bq0 = *(const bf16x8*)qsrc;
  bf16x8 bq1 = *(const bf16x8*)(qsrc + 32);
  __syncthreads();

  // S^T = K Q^T : A-frag = K rows from lKP
  f32x4 sa[16];
#pragma unroll
  for (int kg = 0; kg < 16; ++kg) {
    const __bf16* krow = &lKP[((kg << 4) + l15) << 6];
    bf16x8 a0 = *(const bf16x8*)&krow[(hi << 3) ^ xk];
    bf16x8 a1 = *(const bf16x8*)&krow[(32 + (hi << 3)) ^ xk];
    f32x4 z = {0.f, 0.f, 0.f, 0.f};
    z = __builtin_amdgcn_mfma_f32_16x16x32_bf16(a0, bq0, z, 0, 0, 0);
    sa[kg] = __builtin_amdgcn_mfma_f32_16x16x32_bf16(a1, bq1, z, 0, 0, 0);
  }

  // mask + softmax: lane holds keys 16kg+4hi+{0..3} for query q0w+l15
  float mx = -3.4e38f;
#pragma unroll
  for (int kg = 0; kg < 16; ++kg) {
    f32x4 pm = *(const f32x4*)&lpad[(kg << 4) + (hi << 2)];
#pragma unroll
    for (int j = 0; j < 4; ++j) {
      float v = fmaf(sa[kg][j], 0.125f, -pm[j]);
      sa[kg][j] = v;
      mx = fmaxf(mx, v);
    }
  }
  mx = fmaxf(mx, __shfl_xor(mx, 16));
  mx = fmaxf(mx, __shfl_xor(mx, 32));
  float sum = 0.f;
#pragma unroll
  for (int kg = 0; kg < 16; ++kg)
#pragma unroll
    for (int j = 0; j < 4; ++j) {
      float p = __expf(sa[kg][j] - mx);
      sa[kg][j] = p;
      sum += p;
    }
  sum += __shfl_xor(sum, 16);
  sum += __shfl_xor(sum, 32);
  float dinv = 1.f / sum;   // for query q0w + l15

  __syncthreads();          // all waves done reading K -> lKP becomes P

  // P -> lKP as [64 q][256 keys], row = w*16 + l15 (wave-private rows)
  __bf16* lP = &lKP[(((w << 4) + l15) << 8)];
#pragma unroll
  for (int kg = 0; kg < 16; ++kg) {
    bf16x4 pk;
#pragma unroll
    for (int j = 0; j < 4; ++j) pk[j] = (__bf16)sa[kg][j];
    *(bf16x4*)&lP[(((kg << 4) + (hi << 2)) ^ xk)] = pk;
  }

  // y = P V : A = P[q][k] (row=l15), B = V^T from lVt (col=d=l15)
  f32x4 ya[4] = {};
#pragma unroll
  for (int kc = 0; kc < 8; ++kc) {
    bf16x8 pa = *(const bf16x8*)&lP[(((kc << 5) + (hi << 3)) ^ xk)];
#pragma unroll
    for (int nd = 0; nd < 4; ++nd) {
      bf16x8 vb = *(const bf16x8*)&lVt[(((nd << 4) + l15) << 8) + (((kc << 5) + (hi << 3)) ^ xk)];
      ya[nd] = __builtin_amdgcn_mfma_f32_16x16x32_bf16(pa, vb, ya[nd], 0, 0, 0);
    }
  }

  // dinv for output row q = q0w+4hi+j lives at lane 4hi+j
  float dq[4];
#pragma unroll
  for (int j = 0; j < 4; ++j) dq[j] = __shfl(dinv, (hi << 2) + j);

#pragma unroll
  for (int nd = 0; nd < 4; ++nd) {
    int d = (h << 6) + (nd << 4) + l15;
#pragma unroll
    for (int j = 0; j < 4; ++j) {
      int q = q0w + (hi << 2) + j;
      yT[((size_t)((n << 10) + q) << 10) + d] = (__bf16)(ya[nd][j] * dq[j]);
    }
  }
}

extern "C" void kernel_launch(void* const* d_in, const int* in_sizes, int n_in,
                              void* d_out, int out_size, void* d_ws, size_t ws_size,
                              hipStream_t stream) {
  const float* x         = (const float*)d_in[0];
  const float* enc       = (const float*)d_in[1];
  const int*   padding   = (const int*)d_in[2];
  const float* gamma_dec = (const float*)d_in[3];
  const float* beta_dec  = (const float*)d_in[4];
  const float* gamma_enc = (const float*)d_in[5];
  const float* beta_enc  = (const float*)d_in[6];
  const float* Wq        = (const float*)d_in[7];
  const float* bq        = (const float*)d_in[8];
  const float* Wkv       = (const float*)d_in[9];
  const float* bkv       = (const float*)d_in[10];
  const float* Wo        = (const float*)d_in[11];
  const float* bo        = (const float*)d_in[12];
  float* out = (float*)d_out;

  char* ws = (char*)d_ws;
  __bf16* ndT  = (__bf16*)(ws);
  __bf16* yT   = (__bf16*)(ws);                 // reuse: ndT dead after Q-GEMM
  __bf16* QT   = (__bf16*)(ws + 33554432);
  __bf16* kvb  = (__bf16*)(ws + 67108864);
  __bf16* encn = (__bf16*)(ws + 83886080);
  __bf16* vT   = (__bf16*)(ws + 83886080);      // reuse: encn dead after kv-GEMM
  __bf16* WqB  = (__bf16*)(ws + 92274688);
  __bf16* WkvB = (__bf16*)(ws + 94371840);
  __bf16* WoB  = (__bf16*)(ws + 97517568);
  float*  mu   = (float*)(ws + 99614720);
  float*  rstd = (float*)(ws + 99680256);

  ln_stats_kernel<<<256, 1024, 0, stream>>>(x, mu, rstd);
  norm_transpose_kernel<<<dim3(16, 16, 16), 256, 0, stream>>>(x, mu, rstd, gamma_dec, beta_dec, ndT);
  enc_ln_kernel<<<dim3(256, 16), 256, 0, stream>>>(enc, gamma_enc, beta_enc, encn);
  cast_bf16_kernel<<<512, 256, 0, stream>>>(Wq, WqB, 1024 * 1024);
  cast_bf16_kernel<<<512, 256, 0, stream>>>(Wkv, WkvB, 2048 * 768);
  cast_bf16_kernel<<<512, 256, 0, stream>>>(Wo, WoB, 1024 * 1024);

  // QT[n][p][o] = ndT[n] @ Wq^T + bq
  gemm_bt_kernel<0><<<dim3(8, 8, 16), 256, 0, stream>>>(
      ndT, WqB, bq, nullptr, QT, 1024, 1024, 1024,
      (size_t)1024 * 1024, 0, (size_t)1024 * 1024, 0);
  // kv[n][s][j] = encn[n] @ Wkv^T + bkv
  gemm_bt_kernel<0><<<dim3(16, 2, 16), 256, 0, stream>>>(
      encn, WkvB, bkv, nullptr, kvb, 256, 2048, 768,
      (size_t)256 * 768, 0, (size_t)256 * 2048, 0);

  v_transpose_kernel<<<dim3(16, 16), 256, 0, stream>>>(kvb, vT);

  attn_kernel<<<dim3(16, 16, 16), 256, 0, stream>>>(QT, kvb, vT, padding, yT);

  // out[n][o][p] = x + Wo @ y + bo   (Bt = yT[n][p][c])
  gemm_bt_kernel<1><<<dim3(8, 8, 16), 256, 0, stream>>>(
      WoB, yT, bo, x, out, 1024, 1024, 1024,
      0, (size_t)1024 * 1024, (size_t)1024 * 1024, (size_t)1024 * 1024);
}

// Round 5
// 207.563 us; speedup vs baseline: 1.5009x; 1.1130x over previous
//
#include <hip/hip_runtime.h>
#include <hip/hip_bf16.h>
#include <stdint.h>

// CrossAttention2d: n=16, c=1024, h=w=32 (hw=1024), S=256, c_enc=768, H=16, d=64.
// Pipeline: ln_stats -> norm+transpose(bf16) -> enc LN(bf16) -> cast weights ->
//   QT = ndT @ Wq^T + bq      (gemm256, 4-phase counted-vmcnt schedule)
//   kv = enc_n @ Wkv^T + bkv  (gemm256)
//   vT = transpose(V)
//   attention per (h, qtile, n): K+V^T in LDS, swapped QK^T, in-reg softmax
//   out = x + Wo @ y + bo     (gemm256, fp32 out + residual)

typedef __bf16 bf16x8 __attribute__((ext_vector_type(8)));
typedef __bf16 bf16x4 __attribute__((ext_vector_type(4)));
typedef float f32x4 __attribute__((ext_vector_type(4)));

#define VMCNT(n) asm volatile("s_waitcnt vmcnt(" #n ")" ::: "memory")
#define LGKMCNT0 asm volatile("s_waitcnt lgkmcnt(0)" ::: "memory")

__device__ __forceinline__ void gload_lds16(const void* g, void* l) {
  __builtin_amdgcn_global_load_lds(
      (const __attribute__((address_space(1))) void*)(uintptr_t)g,
      (__attribute__((address_space(3))) void*)(unsigned int)(uintptr_t)l,
      16, 0, 0);
}

__device__ __forceinline__ f32x4 mfma16(bf16x8 a, bf16x8 b, f32x4 c) {
  return __builtin_amdgcn_mfma_f32_16x16x32_bf16(a, b, c, 0, 0, 0);
}

// ---------- LN stats over channels: mu/rstd per (n,p) ----------
__global__ __launch_bounds__(1024) void ln_stats_kernel(const float* __restrict__ x,
                                                        float* __restrict__ mu,
                                                        float* __restrict__ rstd) {
  int b = blockIdx.x;
  int n = b >> 4;
  int p0 = (b & 15) << 6;        // 64 pixels
  int t = threadIdx.x;
  int pl4 = t & 15;              // float4 index within the 64 px
  int cg = t >> 4;               // 0..63 c-group
  const f32x4* xp = (const f32x4*)(x + ((size_t)n << 20) + p0);
  f32x4 s = {0.f, 0.f, 0.f, 0.f}, s2 = {0.f, 0.f, 0.f, 0.f};
#pragma unroll
  for (int i = 0; i < 16; ++i) {
    int c = cg + (i << 6);
    f32x4 v = xp[(c << 8) + pl4];
    s += v;
    s2 += v * v;
  }
  __shared__ f32x4 ls[64][16];
  __shared__ f32x4 ls2[64][16];
  ls[cg][pl4] = s;
  ls2[cg][pl4] = s2;
  __syncthreads();
  if (t < 64) {
    int q = t >> 4, p = t & 15;
    f32x4 a = {0.f, 0.f, 0.f, 0.f}, a2 = {0.f, 0.f, 0.f, 0.f};
#pragma unroll
    for (int i = 0; i < 16; ++i) {
      a += ls[(q << 4) + i][p];
      a2 += ls2[(q << 4) + i][p];
    }
    ls[q][p] = a;
    ls2[q][p] = a2;
  }
  __syncthreads();
  if (t < 16) {
    f32x4 tot = ls[0][t] + ls[1][t] + ls[2][t] + ls[3][t];
    f32x4 tot2 = ls2[0][t] + ls2[1][t] + ls2[2][t] + ls2[3][t];
    f32x4 m, r;
#pragma unroll
    for (int e = 0; e < 4; ++e) {
      float mm = tot[e] * (1.f / 1024.f);
      float var = tot2[e] * (1.f / 1024.f) - mm * mm;
      m[e] = mm;
      r[e] = rsqrtf(var + 1e-5f);
    }
    ((f32x4*)(mu + (n << 10) + p0))[t] = m;
    ((f32x4*)(rstd + (n << 10) + p0))[t] = r;
  }
}

// ---------- normalize + transpose: ndT[n][p][c] bf16 ----------
__global__ __launch_bounds__(256) void norm_transpose_kernel(
    const float* __restrict__ x, const float* __restrict__ mu,
    const float* __restrict__ rstd, const float* __restrict__ gamma,
    const float* __restrict__ beta, __bf16* __restrict__ ndT) {
  int n = blockIdx.z;
  int p0 = blockIdx.x << 6;
  int c0 = blockIdx.y << 6;
  __shared__ float tile[64][65];
  int t = threadIdx.x;
  int fc = t & 15;
  int rr = t >> 4;
  const float* xb = x + ((size_t)n << 20) + ((size_t)c0 << 10) + p0;
#pragma unroll
  for (int i = 0; i < 4; ++i) {
    int cl = (i << 4) + rr;
    f32x4 v = *(const f32x4*)(xb + ((size_t)cl << 10) + (fc << 2));
#pragma unroll
    for (int e = 0; e < 4; ++e) tile[cl][(fc << 2) + e] = v[e];
  }
  int cgp = t & 7;
  int pr = t >> 3;
  float g[8], bb[8];
#pragma unroll
  for (int k = 0; k < 8; ++k) {
    g[k] = gamma[c0 + (cgp << 3) + k];
    bb[k] = beta[c0 + (cgp << 3) + k];
  }
  __syncthreads();
#pragma unroll
  for (int it = 0; it < 2; ++it) {
    int pl = (it << 5) + pr;
    int gp = (n << 10) + p0 + pl;
    float m = mu[gp], r = rstd[gp];
    bf16x8 o;
#pragma unroll
    for (int k = 0; k < 8; ++k)
      o[k] = (__bf16)((tile[(cgp << 3) + k][pl] - m) * r * g[k] + bb[k]);
    *(bf16x8*)(ndT + ((size_t)gp << 10) + c0 + (cgp << 3)) = o;
  }
}

// ---------- enc LayerNorm (last dim 768) -> bf16 ----------
__global__ __launch_bounds__(256) void enc_ln_kernel(const float* __restrict__ enc,
    const float* __restrict__ gamma, const float* __restrict__ beta,
    __bf16* __restrict__ out) {
  int s = blockIdx.x, n = blockIdx.y;
  size_t base = ((size_t)n * 256 + s) * 768;
  int t = threadIdx.x;
  float v0 = enc[base + t], v1 = enc[base + t + 256], v2 = enc[base + t + 512];
  float sum = v0 + v1 + v2, sq = v0 * v0 + v1 * v1 + v2 * v2;
#pragma unroll
  for (int off = 32; off; off >>= 1) {
    sum += __shfl_down(sum, off);
    sq  += __shfl_down(sq, off);
  }
  __shared__ float red[8];
  int w = t >> 6;
  if ((t & 63) == 0) { red[w] = sum; red[4 + w] = sq; }
  __syncthreads();
  float tot  = red[0] + red[1] + red[2] + red[3];
  float tot2 = red[4] + red[5] + red[6] + red[7];
  float m = tot * (1.f / 768.f);
  float var = tot2 * (1.f / 768.f) - m * m;
  float rs = rsqrtf(var + 1e-5f);
  out[base + t]       = (__bf16)((v0 - m) * rs * gamma[t] + beta[t]);
  out[base + t + 256] = (__bf16)((v1 - m) * rs * gamma[t + 256] + beta[t + 256]);
  out[base + t + 512] = (__bf16)((v2 - m) * rs * gamma[t + 512] + beta[t + 512]);
}

// ---------- fp32 -> bf16 cast ----------
__global__ __launch_bounds__(256) void cast_bf16_kernel(const float* __restrict__ in,
                                                        __bf16* __restrict__ out, int count) {
  int stride = gridDim.x * 256;
  for (int i = blockIdx.x * 256 + threadIdx.x; i < count; i += stride)
    out[i] = (__bf16)in[i];
}

// ---------- V transpose: kv[n][s][1024+c] -> vT[n][c][s] ----------
__global__ __launch_bounds__(256) void v_transpose_kernel(const __bf16* __restrict__ kv,
                                                          __bf16* __restrict__ vT) {
  int h = blockIdx.x, n = blockIdx.y;
  __shared__ __bf16 tile[64][264];
  int t = threadIdx.x;
  const __bf16* src = kv + ((size_t)n << 19) + 1024 + (h << 6);
#pragma unroll
  for (int i = 0; i < 8; ++i) {
    int s = (i << 5) + (t >> 3);
    int d8 = (t & 7) << 3;
    bf16x8 v = *(const bf16x8*)(src + ((size_t)s << 11) + d8);
#pragma unroll
    for (int j = 0; j < 8; ++j) tile[d8 + j][s] = v[j];
  }
  __syncthreads();
  __bf16* dst = vT + (((size_t)(n << 10) + (h << 6)) << 8);
  int d = t >> 2, s0 = (t & 3) << 6;
#pragma unroll
  for (int j = 0; j < 8; ++j)
    *(bf16x8*)(dst + ((size_t)d << 8) + s0 + (j << 3)) = *(const bf16x8*)&tile[d][s0 + (j << 3)];
}

// ---------- gemm256: C[M][N] = A[M][K] * Bt[N][K]^T (+bias, +resid) ----------
// 256x256 tile, BK=64, 8 waves (2m x 4n), double-buffered 128 KB LDS,
// 4-phase schedule with counted vmcnt gates (never drains mid-loop).
// Stage order per K-tile: [B0,B1,B2,B3, A0,A2, A1,A3] (8 x gload_lds16/thread);
// phase ph consumes A row-chunks {ph*32, 128+ph*32} (in instrs A0/A2 for ph<2,
// A1/A3 for ph>=2) and B (all, hoisted to regs at ph0).
// Gates: ph0 vmcnt(2), ph1 vmcnt(4), ph2 vmcnt(4), ph3 vmcnt(6) -- uniform
// across waves; s_barrier after each gate makes staged data collectively valid.
// EPI 0: bias per N col, bf16 out. EPI 1: bias per M row + fp32 resid, fp32 out.
template <int EPI>
__global__ __launch_bounds__(512, 2) void gemm256_kernel(
    const __bf16* __restrict__ A, const __bf16* __restrict__ Bt,
    const float* __restrict__ bias, const float* __restrict__ resid,
    void* __restrict__ Cout, int M, int N, int K,
    size_t sA, size_t sB, size_t sC, size_t sR) {
  int n0 = blockIdx.x << 8;
  int m0 = blockIdx.y << 8;
  int bz = blockIdx.z;
  const __bf16* Ab = A + sA * bz;
  const __bf16* Bb = Bt + sB * bz;

  int tid = threadIdx.x;
  int w = tid >> 6, lane = tid & 63;
  int l15 = lane & 15, hi = lane >> 4;
  int wm = w >> 2, wn = w & 3;   // 2 x 4 wave grid; per-wave out 128 x 64

  __shared__ __align__(16) __bf16 lA[2][256 * 64];
  __shared__ __align__(16) __bf16 lB[2][256 * 64];

  f32x4 acc[8][4] = {};
  int xk = (l15 & 7) << 3;
  int ka0 = (hi << 3) ^ xk;
  int ka1 = (32 + (hi << 3)) ^ xk;
  int NT = K >> 6;

  auto stageA = [&](int buf, int a, int kt) {
    int e = (a << 12) + (tid << 3);
    int r = e >> 6, c = e & 63;
    int cs = c ^ ((r & 7) << 3);
    gload_lds16(Ab + (size_t)(m0 + r) * K + kt + cs, &lA[buf][e]);
  };
  auto stageB = [&](int buf, int b, int kt) {
    int e = (b << 12) + (tid << 3);
    int r = e >> 6, c = e & 63;
    int cs = c ^ ((r & 7) << 3);
    gload_lds16(Bb + (size_t)(n0 + r) * K + kt + cs, &lB[buf][e]);
  };

  // prologue: tile 0 in stage order
  stageB(0, 0, 0); stageB(0, 1, 0); stageB(0, 2, 0); stageB(0, 3, 0);
  stageA(0, 0, 0); stageA(0, 2, 0); stageA(0, 1, 0); stageA(0, 3, 0);

  for (int t = 0; t < NT - 1; ++t) {
    int cur = t & 1;
    int nxt = cur ^ 1;
    int kn = (t + 1) << 6;
    bf16x8 bfr[4][2];
#pragma unroll
    for (int ph = 0; ph < 4; ++ph) {
      if (ph == 0)      { VMCNT(2); }
      else if (ph == 1) { VMCNT(4); }
      else if (ph == 2) { VMCNT(4); }
      else              { VMCNT(6); }
      __builtin_amdgcn_s_barrier();
      __builtin_amdgcn_sched_barrier(0);
      if (ph == 0)      { stageB(nxt, 0, kn); stageB(nxt, 1, kn); }
      else if (ph == 1) { stageB(nxt, 2, kn); stageB(nxt, 3, kn); }
      else if (ph == 2) { stageA(nxt, 0, kn); stageA(nxt, 2, kn); }
      else              { stageA(nxt, 1, kn); stageA(nxt, 3, kn); }
      if (ph == 0) {
#pragma unroll
        for (int ni = 0; ni < 4; ++ni) {
          int row = (wn << 6) + (ni << 4) + l15;
          bfr[ni][0] = *(const bf16x8*)&lB[cur][(row << 6) + ka0];
          bfr[ni][1] = *(const bf16x8*)&lB[cur][(row << 6) + ka1];
        }
      }
      bf16x8 af[2][2];
#pragma unroll
      for (int i = 0; i < 2; ++i) {
        int row = (wm << 7) + (((ph << 1) + i) << 4) + l15;
        af[i][0] = *(const bf16x8*)&lA[cur][(row << 6) + ka0];
        af[i][1] = *(const bf16x8*)&lA[cur][(row << 6) + ka1];
      }
      LGKMCNT0;
      __builtin_amdgcn_sched_barrier(0);
      __builtin_amdgcn_s_setprio(1);
#pragma unroll
      for (int i = 0; i < 2; ++i)
#pragma unroll
        for (int ni = 0; ni < 4; ++ni) {
          int m = (ph << 1) + i;
          acc[m][ni] = mfma16(af[i][0], bfr[ni][0], acc[m][ni]);
          acc[m][ni] = mfma16(af[i][1], bfr[ni][1], acc[m][ni]);
        }
      __builtin_amdgcn_s_setprio(0);
      __builtin_amdgcn_sched_barrier(0);
    }
  }

  // peeled final tile: no staging; gates drain what's needed
  {
    int cur = (NT - 1) & 1;
    bf16x8 bfr[4][2];
#pragma unroll
    for (int ph = 0; ph < 4; ++ph) {
      if (ph == 0)      { VMCNT(2); }
      else if (ph == 1) { VMCNT(2); }
      else              { VMCNT(0); }
      __builtin_amdgcn_s_barrier();
      __builtin_amdgcn_sched_barrier(0);
      if (ph == 0) {
#pragma unroll
        for (int ni = 0; ni < 4; ++ni) {
          int row = (wn << 6) + (ni << 4) + l15;
          bfr[ni][0] = *(const bf16x8*)&lB[cur][(row << 6) + ka0];
          bfr[ni][1] = *(const bf16x8*)&lB[cur][(row << 6) + ka1];
        }
      }
      bf16x8 af[2][2];
#pragma unroll
      for (int i = 0; i < 2; ++i) {
        int row = (wm << 7) + (((ph << 1) + i) << 4) + l15;
        af[i][0] = *(const bf16x8*)&lA[cur][(row << 6) + ka0];
        af[i][1] = *(const bf16x8*)&lA[cur][(row << 6) + ka1];
      }
      LGKMCNT0;
      __builtin_amdgcn_sched_barrier(0);
      __builtin_amdgcn_s_setprio(1);
#pragma unroll
      for (int i = 0; i < 2; ++i)
#pragma unroll
        for (int ni = 0; ni < 4; ++ni) {
          int m = (ph << 1) + i;
          acc[m][ni] = mfma16(af[i][0], bfr[ni][0], acc[m][ni]);
          acc[m][ni] = mfma16(af[i][1], bfr[ni][1], acc[m][ni]);
        }
      __builtin_amdgcn_s_setprio(0);
      __builtin_amdgcn_sched_barrier(0);
    }
  }

#pragma unroll
  for (int m = 0; m < 8; ++m) {
#pragma unroll
    for (int ni = 0; ni < 4; ++ni) {
      int col = n0 + (wn << 6) + (ni << 4) + l15;
      int rbase = m0 + (wm << 7) + (m << 4) + (hi << 2);
      if (EPI == 0) {
        float bb = bias[col];
        __bf16* C = (__bf16*)Cout + sC * bz;
#pragma unroll
        for (int j = 0; j < 4; ++j)
          C[(size_t)(rbase + j) * N + col] = (__bf16)(acc[m][ni][j] + bb);
      } else {
        float* C = (float*)Cout + sC * bz;
        const float* R = resid + sR * bz;
#pragma unroll
        for (int j = 0; j < 4; ++j) {
          int row = rbase + j;
          C[(size_t)row * N + col] = acc[m][ni][j] + bias[row] + R[(size_t)row * N + col];
        }
      }
    }
  }
}

// ---------- attention: LDS-staged K/V^T, swapped QK^T, P aliases K ----------
__global__ __launch_bounds__(256, 2) void attn_kernel(
    const __bf16* __restrict__ QT,   // [n][1024][1024]
    const __bf16* __restrict__ kv,   // [n][256][2048] (K part: cols 0..1023)
    const __bf16* __restrict__ vT,   // [n][1024][256]
    const int* __restrict__ padding, // [n][256]
    __bf16* __restrict__ yT) {       // [n][1024][1024]
  int h = blockIdx.x, qb = blockIdx.y, n = blockIdx.z;
  int tid = threadIdx.x;
  int w = tid >> 6, lane = tid & 63;
  int l15 = lane & 15, hi = lane >> 4;
  int xk = (l15 & 7) << 3;

  __shared__ __align__(16) __bf16 lKP[256 * 64];  // K; later P [64 q][256 keys]
  __shared__ __align__(16) __bf16 lVt[64 * 256];  // V^T [64 d][256 keys]
  __shared__ __align__(16) float lpad[256];

  const __bf16* kvb = kv + ((size_t)n << 19);
#pragma unroll
  for (int i = 0; i < 8; ++i) {
    int e = ((i << 8) + tid) << 3;
    int r = e >> 6;
    int c = e & 63;
    int cs = c ^ ((r & 7) << 3);
    gload_lds16(kvb + ((size_t)r << 11) + (h << 6) + cs, &lKP[e]);
  }
  const __bf16* vtb = vT + (((size_t)(n << 10) + (h << 6)) << 8);
#pragma unroll
  for (int i = 0; i < 8; ++i) {
    int e = ((i << 8) + tid) << 3;
    int r = e >> 8;
    int c = e & 255;
    int cs = c ^ ((r & 7) << 3);
    gload_lds16(vtb + ((size_t)r << 8) + cs, &lVt[e]);
  }
  lpad[tid] = 10000.f * (float)padding[(n << 8) + tid];

  int q0w = (qb << 6) + (w << 4);
  const __bf16* qsrc = QT + ((size_t)((n << 10) + q0w + l15) << 10) + (h << 6) + (hi << 3);
  bf16x8 bq0 = *(const bf16x8*)qsrc;
  bf16x8 bq1 = *(const bf16x8*)(qsrc + 32);
  __syncthreads();

  f32x4 sa[16];
#pragma unroll
  for (int kg = 0; kg < 16; ++kg) {
    const __bf16* krow = &lKP[((kg << 4) + l15) << 6];
    bf16x8 a0 = *(const bf16x8*)&krow[(hi << 3) ^ xk];
    bf16x8 a1 = *(const bf16x8*)&krow[(32 + (hi << 3)) ^ xk];
    f32x4 z = {0.f, 0.f, 0.f, 0.f};
    z = mfma16(a0, bq0, z);
    sa[kg] = mfma16(a1, bq1, z);
  }

  float mx = -3.4e38f;
#pragma unroll
  for (int kg = 0; kg < 16; ++kg) {
    f32x4 pm = *(const f32x4*)&lpad[(kg << 4) + (hi << 2)];
#pragma unroll
    for (int j = 0; j < 4; ++j) {
      float v = fmaf(sa[kg][j], 0.125f, -pm[j]);
      sa[kg][j] = v;
      mx = fmaxf(mx, v);
    }
  }
  mx = fmaxf(mx, __shfl_xor(mx, 16));
  mx = fmaxf(mx, __shfl_xor(mx, 32));
  float sum = 0.f;
#pragma unroll
  for (int kg = 0; kg < 16; ++kg)
#pragma unroll
    for (int j = 0; j < 4; ++j) {
      float p = __expf(sa[kg][j] - mx);
      sa[kg][j] = p;
      sum += p;
    }
  sum += __shfl_xor(sum, 16);
  sum += __shfl_xor(sum, 32);
  float dinv = 1.f / sum;

  __syncthreads();          // all waves done reading K -> lKP becomes P

  __bf16* lP = &lKP[(((w << 4) + l15) << 8)];
#pragma unroll
  for (int kg = 0; kg < 16; ++kg) {
    bf16x4 pk;
#pragma unroll
    for (int j = 0; j < 4; ++j) pk[j] = (__bf16)sa[kg][j];
    *(bf16x4*)&lP[(((kg << 4) + (hi << 2)) ^ xk)] = pk;
  }

  f32x4 ya[4] = {};
#pragma unroll
  for (int kc = 0; kc < 8; ++kc) {
    bf16x8 pa = *(const bf16x8*)&lP[(((kc << 5) + (hi << 3)) ^ xk)];
#pragma unroll
    for (int nd = 0; nd < 4; ++nd) {
      bf16x8 vb = *(const bf16x8*)&lVt[(((nd << 4) + l15) << 8) + (((kc << 5) + (hi << 3)) ^ xk)];
      ya[nd] = mfma16(pa, vb, ya[nd]);
    }
  }

  float dq[4];
#pragma unroll
  for (int j = 0; j < 4; ++j) dq[j] = __shfl(dinv, (hi << 2) + j);

#pragma unroll
  for (int nd = 0; nd < 4; ++nd) {
    int d = (h << 6) + (nd << 4) + l15;
#pragma unroll
    for (int j = 0; j < 4; ++j) {
      int q = q0w + (hi << 2) + j;
      yT[((size_t)((n << 10) + q) << 10) + d] = (__bf16)(ya[nd][j] * dq[j]);
    }
  }
}

extern "C" void kernel_launch(void* const* d_in, const int* in_sizes, int n_in,
                              void* d_out, int out_size, void* d_ws, size_t ws_size,
                              hipStream_t stream) {
  const float* x         = (const float*)d_in[0];
  const float* enc       = (const float*)d_in[1];
  const int*   padding   = (const int*)d_in[2];
  const float* gamma_dec = (const float*)d_in[3];
  const float* beta_dec  = (const float*)d_in[4];
  const float* gamma_enc = (const float*)d_in[5];
  const float* beta_enc  = (const float*)d_in[6];
  const float* Wq        = (const float*)d_in[7];
  const float* bq        = (const float*)d_in[8];
  const float* Wkv       = (const float*)d_in[9];
  const float* bkv       = (const float*)d_in[10];
  const float* Wo        = (const float*)d_in[11];
  const float* bo        = (const float*)d_in[12];
  float* out = (float*)d_out;

  char* ws = (char*)d_ws;
  __bf16* ndT  = (__bf16*)(ws);
  __bf16* yT   = (__bf16*)(ws);                 // reuse: ndT dead after Q-GEMM
  __bf16* QT   = (__bf16*)(ws + 33554432);
  __bf16* kvb  = (__bf16*)(ws + 67108864);
  __bf16* encn = (__bf16*)(ws + 83886080);
  __bf16* vT   = (__bf16*)(ws + 83886080);      // reuse: encn dead after kv-GEMM
  __bf16* WqB  = (__bf16*)(ws + 92274688);
  __bf16* WkvB = (__bf16*)(ws + 94371840);
  __bf16* WoB  = (__bf16*)(ws + 97517568);
  float*  mu   = (float*)(ws + 99614720);
  float*  rstd = (float*)(ws + 99680256);

  ln_stats_kernel<<<256, 1024, 0, stream>>>(x, mu, rstd);
  norm_transpose_kernel<<<dim3(16, 16, 16), 256, 0, stream>>>(x, mu, rstd, gamma_dec, beta_dec, ndT);
  enc_ln_kernel<<<dim3(256, 16), 256, 0, stream>>>(enc, gamma_enc, beta_enc, encn);
  cast_bf16_kernel<<<512, 256, 0, stream>>>(Wq, WqB, 1024 * 1024);
  cast_bf16_kernel<<<512, 256, 0, stream>>>(Wkv, WkvB, 2048 * 768);
  cast_bf16_kernel<<<512, 256, 0, stream>>>(Wo, WoB, 1024 * 1024);

  // QT[n][p][o] = ndT[n] @ Wq^T + bq
  gemm256_kernel<0><<<dim3(4, 4, 16), 512, 0, stream>>>(
      ndT, WqB, bq, nullptr, QT, 1024, 1024, 1024,
      (size_t)1024 * 1024, 0, (size_t)1024 * 1024, 0);
  // kv[n][s][j] = encn[n] @ Wkv^T + bkv
  gemm256_kernel<0><<<dim3(8, 1, 16), 512, 0, stream>>>(
      encn, WkvB, bkv, nullptr, kvb, 256, 2048, 768,
      (size_t)256 * 768, 0, (size_t)256 * 2048, 0);

  v_transpose_kernel<<<dim3(16, 16), 256, 0, stream>>>(kvb, vT);

  attn_kernel<<<dim3(16, 16, 16), 256, 0, stream>>>(QT, kvb, vT, padding, yT);

  // out[n][o][p] = x + Wo @ y + bo   (Bt = yT[n][p][c])
  gemm256_kernel<1><<<dim3(4, 4, 16), 512, 0, stream>>>(
      WoB, yT, bo, x, out, 1024, 1024, 1024,
      0, (size_t)1024 * 1024, (size_t)1024 * 1024, (size_t)1024 * 1024);
}